// Round 6
// baseline (220.421 us; speedup 1.0000x reference)
//
#include <hip/hip_runtime.h>
#include <hip/hip_bf16.h>

// Problem constants
#define NB   8      // batch
#define NL   1024   // sequence length
#define ND   256    // model dim
#define NH   8      // heads
#define NHD  64     // head dim
#define NC   512    // NH*NHD
#define NTOK (NB*NL) // 8192

typedef __bf16 bf16x8v __attribute__((ext_vector_type(8)));
typedef float f32x4 __attribute__((ext_vector_type(4)));

__device__ __forceinline__ unsigned short f2bf(float f) {
  unsigned u = __float_as_uint(f);
  unsigned r = (u + 0x7fffu + ((u >> 16) & 1u)) >> 16;
  return (unsigned short)r;
}

// pack two f32 -> bf16x2 (elem0 in low 16 bits)
__device__ __forceinline__ unsigned pack_bf16x2(float lo, float hi) {
  __hip_bfloat162 h2 = __float22bfloat162_rn(make_float2(lo, hi));
  union { __hip_bfloat162 h; unsigned u; } cvt;
  cvt.h = h2;
  return cvt.u;
}

// ---------------------------------------------------------------------------
// Fused prep.
// Blocks [0,1024): 8 elems/thread: xpe = bf16(x + PE), xb = bf16(x).
//   PE via fast HW trig (__sinf/__cosf): phase error <=1.2e-4 rad at l=1023,
//   far below bf16 rounding (~4e-3).
// Blocks [1024,1120): LDS-tiled 64x64 transpose: Wt[n][k] = bf16(W[k][n])
//   for the 3 weight matrices (coalesced reads AND writes).
// ---------------------------------------------------------------------------
__global__ __launch_bounds__(256) void prep_kernel(
    const float* __restrict__ x,
    const float* __restrict__ Wq, const float* __restrict__ Wk,
    const float* __restrict__ Wv,
    unsigned short* __restrict__ xpe, unsigned short* __restrict__ xb,
    unsigned short* __restrict__ wqt, unsigned short* __restrict__ wkt,
    unsigned short* __restrict__ wvt) {
  const int bid = blockIdx.x;
  const int tid = threadIdx.x;
  if (bid < (NTOK * ND) / (256 * 8)) {
    int idx = bid * 256 + tid;        // 0 .. 262143, 8 elems each
    int d0 = (idx & 31) * 8;          // 32 chunks of 8 dims per token
    int t = idx >> 5;                 // token
    int l = t & (NL - 1);
    float4 xa = *(const float4*)(x + (size_t)t * ND + d0);
    float4 xc = *(const float4*)(x + (size_t)t * ND + d0 + 4);
    float xv[8] = {xa.x, xa.y, xa.z, xa.w, xc.x, xc.y, xc.z, xc.w};
    unsigned short pe_out[8], xb_out[8];
#pragma unroll
    for (int p = 0; p < 4; ++p) {
      // exponent index = d>>1 = d0/2 + p  (shared by the sin/cos pair)
      float inv_dim = __expf(-0.07195578415606394f * (float)(d0 / 2 + p));
      float ang = (float)l * inv_dim;
      float sv = __sinf(ang);
      float cv = __cosf(ang);
      pe_out[2 * p]     = f2bf(xv[2 * p] + sv);
      pe_out[2 * p + 1] = f2bf(xv[2 * p + 1] + cv);
      xb_out[2 * p]     = f2bf(xv[2 * p]);
      xb_out[2 * p + 1] = f2bf(xv[2 * p + 1]);
    }
    *(int4*)(xpe + (size_t)t * ND + d0) = *(int4*)pe_out;
    *(int4*)(xb  + (size_t)t * ND + d0) = *(int4*)xb_out;
  } else {
    __shared__ float tile[64 * 65];
    int widx = bid - (NTOK * ND) / (256 * 8);   // 0..95
    int m = widx >> 5;                          // matrix 0..2
    int tl = widx & 31;                         // 0..31
    int kt = tl & 3;                            // k-tile (256/64)
    int nt = tl >> 2;                           // n-tile (512/64)
    const float* W = (m == 0) ? Wq : (m == 1) ? Wk : Wv;
    unsigned short* Wt = (m == 0) ? wqt : (m == 1) ? wkt : wvt;
    int c = tid & 63, rb = tid >> 6;
#pragma unroll
    for (int i = 0; i < 16; ++i) {
      int r = i * 4 + rb;   // k_local
      tile[r * 65 + c] = W[(kt * 64 + r) * NC + nt * 64 + c];
    }
    __syncthreads();
#pragma unroll
    for (int i = 0; i < 16; ++i) {
      int n_local = i * 4 + rb, k_local = c;
      Wt[(nt * 64 + n_local) * ND + kt * 64 + k_local] =
          f2bf(tile[k_local * 65 + n_local]);
    }
  }
}

// ---------------------------------------------------------------------------
// Fused QKV projection GEMM: grid.z in {0:q, 1:k, 2:v}
// Out = (X[8192x256] * W[256x512] + bias_per_head) * scale
// MFMA 16x16x32 bf16, tile 128(M) x 64(N), BK=64, 4 waves.
// Register double-buffer: kb+1 global loads issue before kb's MFMA block.
// z<2: Out[(b,h,l,d)]   z==2 (v): Out[(b,h,d,l)] (transposed for attention)
// q additionally folds attention scale AND log2(e) (softmax in exp2 domain).
// ---------------------------------------------------------------------------
__global__ __launch_bounds__(256) void gemm_qkv_kernel(
    const unsigned short* __restrict__ xpe, const unsigned short* __restrict__ xb,
    const unsigned short* __restrict__ wqt, const unsigned short* __restrict__ wkt,
    const unsigned short* __restrict__ wvt,
    const float* __restrict__ bq, const float* __restrict__ bk,
    const float* __restrict__ bv,
    unsigned short* __restrict__ qg, unsigned short* __restrict__ kg,
    unsigned short* __restrict__ vg) {
  __shared__ unsigned short As[128 * 72];
  __shared__ unsigned short Bs[64 * 72];

  const int z = blockIdx.z;
  const unsigned short* X  = (z == 2) ? xb : xpe;
  const unsigned short* Wt = (z == 0) ? wqt : (z == 1) ? wkt : wvt;
  const float* bias        = (z == 0) ? bq  : (z == 1) ? bk  : bv;
  unsigned short* Out      = (z == 0) ? qg  : (z == 1) ? kg  : vg;
  // q: 1/sqrt(64) * log2(e)  (exp2-domain softmax)
  const float scale        = (z == 0) ? 0.18033688011112042f : 1.0f;

  const int nt = blockIdx.x;     // 0..7   N tile
  const int mt = blockIdx.y;     // 0..63  M tile
  const int tid = threadIdx.x;
  const int w = tid >> 6;
  const int lane = tid & 63;
  const int lg = lane >> 4;      // 0..3
  const int lr = lane & 15;      // 0..15

  f32x4 acc[2][4] = {};
  int4 areg[4], breg[2];

  auto load_tiles = [&](int kb) {
#pragma unroll
    for (int i = 0; i < 4; ++i) {
      int slot = tid + i * 256;
      int r = slot >> 3, c8 = slot & 7;
      areg[i] = *(const int4*)(X + (mt * 128 + r) * ND + kb * 64 + c8 * 8);
    }
#pragma unroll
    for (int i = 0; i < 2; ++i) {
      int slot = tid + i * 256;
      int r = slot >> 3, c8 = slot & 7;
      breg[i] = *(const int4*)(Wt + (nt * 64 + r) * ND + kb * 64 + c8 * 8);
    }
  };

  load_tiles(0);
#pragma unroll
  for (int kb = 0; kb < 4; ++kb) {
    if (kb) __syncthreads();
#pragma unroll
    for (int i = 0; i < 4; ++i) {
      int slot = tid + i * 256;
      int r = slot >> 3, c8 = slot & 7;
      *(int4*)(As + r * 72 + c8 * 8) = areg[i];
    }
#pragma unroll
    for (int i = 0; i < 2; ++i) {
      int slot = tid + i * 256;
      int r = slot >> 3, c8 = slot & 7;
      *(int4*)(Bs + r * 72 + c8 * 8) = breg[i];
    }
    if (kb < 3) load_tiles(kb + 1);
    __syncthreads();

#pragma unroll
    for (int kk = 0; kk < 2; ++kk) {
      bf16x8v a[2], b[4];
#pragma unroll
      for (int mi = 0; mi < 2; ++mi)
        a[mi] = *(const bf16x8v*)(As + (w * 32 + mi * 16 + lr) * 72 + kk * 32 + lg * 8);
#pragma unroll
      for (int nb = 0; nb < 4; ++nb)
        b[nb] = *(const bf16x8v*)(Bs + (nb * 16 + lr) * 72 + kk * 32 + lg * 8);
#pragma unroll
      for (int mi = 0; mi < 2; ++mi)
#pragma unroll
        for (int nb = 0; nb < 4; ++nb)
          acc[mi][nb] = __builtin_amdgcn_mfma_f32_16x16x32_bf16(
              a[mi], b[nb], acc[mi][nb], 0, 0, 0);
    }
  }

  // C row = (lane>>4)*4 + j, col = lane&15  [HW-verified layout]
#pragma unroll
  for (int mi = 0; mi < 2; ++mi) {
#pragma unroll
    for (int nb = 0; nb < 4; ++nb) {
#pragma unroll
      for (int j = 0; j < 4; ++j) {
        int r = mt * 128 + w * 32 + mi * 16 + lg * 4 + j;   // token index
        int c = nt * 64 + nb * 16 + lr;                     // column in [0,512)
        int bb = r >> 10, lpos = r & (NL - 1);
        int h = c >> 6, dd = c & 63;
        float val = (acc[mi][nb][j] + bias[h]) * scale;
        if (z < 2)
          Out[((bb * NH + h) * NL + lpos) * NHD + dd] = f2bf(val);
        else
          Out[((bb * NH + h) * NHD + dd) * NL + lpos] = f2bf(val);
      }
    }
  }
}

// ---------------------------------------------------------------------------
// Flash attention, swapped-operand + exp2-domain + defer-max + async staging.
// grid (16 q-tiles, 64 bh), 4 waves; each wave owns 16 q-rows.
//   S^T = mfma(kf, qf): lane(lr,lg) holds S[q=lr][k=16nb+4lg+j] (log2 units)
//   O^T = mfma(vf, pf): lane(lr,lg) holds O[d=16db+4lg+j][q=lr]
// K/V tiles reg-double-buffered: tile t+1 global loads in flight during
// tile t compute. Defer-max (THR=8 in log2 units -> P<=256, f32-safe).
// ---------------------------------------------------------------------------
__global__ __launch_bounds__(256) void attn_kernel(
    const unsigned short* __restrict__ Q,
    const unsigned short* __restrict__ K,
    const unsigned short* __restrict__ Vt,
    float* __restrict__ Out) {
  __shared__ unsigned short Ks[64 * 72];
  __shared__ unsigned short Vs[64 * 72];
  __shared__ unsigned short Ps[64 * 72];

  const int qt = blockIdx.x;   // 0..15
  const int bh = blockIdx.y;   // 0..63
  const int bb = bh >> 3, h = bh & 7;
  const int tid = threadIdx.x;
  const int w = tid >> 6;
  const int lane = tid & 63;
  const int lg = lane >> 4, lr = lane & 15;
  const int qrow0 = qt * 64 + w * 16;

  // Q B-fragment: row = lr, k-slice = lg*8 within each 32-block
  bf16x8v qf[2];
#pragma unroll
  for (int kk = 0; kk < 2; ++kk)
    qf[kk] = *(const bf16x8v*)(Q + ((size_t)bh * NL + qrow0 + lr) * NHD + kk * 32 + lg * 8);

  float m_ = -1e30f, lsum = 0.0f;
  f32x4 o[4] = {};

  int4 kreg[2], vreg[2];
  auto load_kv = [&](int kv) {
#pragma unroll
    for (int i = 0; i < 2; ++i) {
      int slot = tid + i * 256;
      int r = slot >> 3, c8 = slot & 7;
      kreg[i] = *(const int4*)(K + ((size_t)bh * NL + kv * 64 + r) * NHD + c8 * 8);
      vreg[i] = *(const int4*)(Vt + ((size_t)bh * NHD + r) * NL + kv * 64 + c8 * 8);
    }
  };

  load_kv(0);
  for (int kv = 0; kv < 16; ++kv) {
    if (kv) __syncthreads();          // all waves done with previous tile
#pragma unroll
    for (int i = 0; i < 2; ++i) {
      int slot = tid + i * 256;
      int r = slot >> 3, c8 = slot & 7;
      *(int4*)(Ks + r * 72 + c8 * 8) = kreg[i];
      *(int4*)(Vs + r * 72 + c8 * 8) = vreg[i];
    }
    if (kv < 15) load_kv(kv + 1);     // next tile loads fly during compute
    __syncthreads();

    // S^T = K * Q^T (log2 units; scale*log2e folded into Q)
    f32x4 s[4] = {};
#pragma unroll
    for (int kk = 0; kk < 2; ++kk) {
#pragma unroll
      for (int nb = 0; nb < 4; ++nb) {
        bf16x8v kf = *(const bf16x8v*)(Ks + (nb * 16 + lr) * 72 + kk * 32 + lg * 8);
        s[nb] = __builtin_amdgcn_mfma_f32_16x16x32_bf16(kf, qf[kk], s[nb], 0, 0, 0);
      }
    }

    // Online softmax, exp2 domain, defer-max (wave-uniform rescale decision)
    float tm = s[0][0];
#pragma unroll
    for (int nb = 0; nb < 4; ++nb)
#pragma unroll
      for (int j = 0; j < 4; ++j) tm = fmaxf(tm, s[nb][j]);
    tm = fmaxf(tm, __shfl_xor(tm, 16, 64));
    tm = fmaxf(tm, __shfl_xor(tm, 32, 64));
    if (__any(tm > m_ + 8.0f)) {
      float nm = fmaxf(m_, tm);
      float corr = exp2f(m_ - nm);
      m_ = nm;
      lsum *= corr;
#pragma unroll
      for (int db = 0; db < 4; ++db)
#pragma unroll
        for (int j = 0; j < 4; ++j) o[db][j] *= corr;
    }
    float ts = 0.0f;
#pragma unroll
    for (int nb = 0; nb < 4; ++nb)
#pragma unroll
      for (int j = 0; j < 4; ++j) {
        float p = exp2f(s[nb][j] - m_);
        s[nb][j] = p;
        ts += p;
      }
    ts += __shfl_xor(ts, 16, 64);
    ts += __shfl_xor(ts, 32, 64);
    lsum += ts;

    // P row q=lr -> LDS packed u32 (wave-private rows; no barrier needed)
#pragma unroll
    for (int nb = 0; nb < 4; ++nb)
#pragma unroll
      for (int hh = 0; hh < 2; ++hh)
        *(unsigned*)(Ps + (w * 16 + lr) * 72 + nb * 16 + lg * 4 + 2 * hh) =
            pack_bf16x2(s[nb][2 * hh], s[nb][2 * hh + 1]);

    // O^T += V^T * P^T
#pragma unroll
    for (int kk = 0; kk < 2; ++kk) {
      bf16x8v pf = *(const bf16x8v*)(Ps + (w * 16 + lr) * 72 + kk * 32 + lg * 8);
#pragma unroll
      for (int db = 0; db < 4; ++db) {
        bf16x8v vf = *(const bf16x8v*)(Vs + (db * 16 + lr) * 72 + kk * 32 + lg * 8);
        o[db] = __builtin_amdgcn_mfma_f32_16x16x32_bf16(vf, pf, o[db], 0, 0, 0);
      }
    }
  }

  // Normalize (scalar per lane) and write out[B, L, 512] f32 as float4s
  float inv = 1.0f / lsum;
  int q = qrow0 + lr;
#pragma unroll
  for (int db = 0; db < 4; ++db) {
    f32x4 ov;
#pragma unroll
    for (int j = 0; j < 4; ++j) ov[j] = o[db][j] * inv;
    *(f32x4*)(Out + (size_t)(bb * NL + q) * NC + h * NHD + db * 16 + lg * 4) = ov;
  }
}

// ---------------------------------------------------------------------------
extern "C" void kernel_launch(void* const* d_in, const int* in_sizes, int n_in,
                              void* d_out, int out_size, void* d_ws, size_t ws_size,
                              hipStream_t stream) {
  const float* x  = (const float*)d_in[0];
  const float* Wq = (const float*)d_in[1];
  const float* bq = (const float*)d_in[2];
  const float* Wk = (const float*)d_in[3];
  const float* bk = (const float*)d_in[4];
  const float* Wv = (const float*)d_in[5];
  const float* bv = (const float*)d_in[6];
  float* out = (float*)d_out;

  // Workspace layout (all bf16 stored as ushort)
  unsigned short* xpe = (unsigned short*)d_ws;        // 2M elems
  unsigned short* xb  = xpe + (size_t)NTOK * ND;      // 2M
  unsigned short* wqt = xb  + (size_t)NTOK * ND;      // 128K
  unsigned short* wkt = wqt + (size_t)ND * NC;
  unsigned short* wvt = wkt + (size_t)ND * NC;
  unsigned short* qg  = wvt + (size_t)ND * NC;        // 512K each
  unsigned short* kg  = qg  + (size_t)NB * NH * NL * NHD;
  unsigned short* vg  = kg  + (size_t)NB * NH * NL * NHD;

  int prep_blocks = (NTOK * ND) / (256 * 8) + 96;   // 1024 + 96
  prep_kernel<<<prep_blocks, 256, 0, stream>>>(x, Wq, Wk, Wv, xpe, xb, wqt, wkt, wvt);

  gemm_qkv_kernel<<<dim3(8, 64, 3), 256, 0, stream>>>(
      xpe, xb, wqt, wkt, wvt, bq, bk, bv, qg, kg, vg);

  attn_kernel<<<dim3(16, 64), 256, 0, stream>>>(qg, kg, vg, out);
}

// Round 7
// 142.266 us; speedup vs baseline: 1.5494x; 1.5494x over previous
//
#include <hip/hip_runtime.h>
#include <hip/hip_bf16.h>

// Problem constants
#define NB   8      // batch
#define NL   1024   // sequence length
#define ND   256    // model dim
#define NH   8      // heads
#define NHD  64     // head dim
#define NC   512    // NH*NHD
#define NTOK (NB*NL) // 8192

typedef __bf16 bf16x8v __attribute__((ext_vector_type(8)));
typedef float f32x4 __attribute__((ext_vector_type(4)));

__device__ __forceinline__ unsigned short f2bf(float f) {
  unsigned u = __float_as_uint(f);
  unsigned r = (u + 0x7fffu + ((u >> 16) & 1u)) >> 16;
  return (unsigned short)r;
}

// pack two f32 -> bf16x2 (elem0 in low 16 bits)
__device__ __forceinline__ unsigned pack_bf16x2(float lo, float hi) {
  __hip_bfloat162 h2 = __float22bfloat162_rn(make_float2(lo, hi));
  union { __hip_bfloat162 h; unsigned u; } cvt;
  cvt.h = h2;
  return cvt.u;
}

// ---------------------------------------------------------------------------
// Fused prep.
// Blocks [0,1024): 8 elems/thread: xpe = bf16(x + PE), xb = bf16(x).
// Blocks [1024,1120): LDS-tiled 64x64 transpose: Wt[n][k] = bf16(W[k][n]).
// ---------------------------------------------------------------------------
__global__ __launch_bounds__(256) void prep_kernel(
    const float* __restrict__ x,
    const float* __restrict__ Wq, const float* __restrict__ Wk,
    const float* __restrict__ Wv,
    unsigned short* __restrict__ xpe, unsigned short* __restrict__ xb,
    unsigned short* __restrict__ wqt, unsigned short* __restrict__ wkt,
    unsigned short* __restrict__ wvt) {
  const int bid = blockIdx.x;
  const int tid = threadIdx.x;
  if (bid < (NTOK * ND) / (256 * 8)) {
    int idx = bid * 256 + tid;        // 0 .. 262143, 8 elems each
    int d0 = (idx & 31) * 8;          // 32 chunks of 8 dims per token
    int t = idx >> 5;                 // token
    int l = t & (NL - 1);
    float4 xa = *(const float4*)(x + (size_t)t * ND + d0);
    float4 xc = *(const float4*)(x + (size_t)t * ND + d0 + 4);
    float xv[8] = {xa.x, xa.y, xa.z, xa.w, xc.x, xc.y, xc.z, xc.w};
    unsigned short pe_out[8], xb_out[8];
#pragma unroll
    for (int p = 0; p < 4; ++p) {
      // exponent index = d>>1 = d0/2 + p  (shared by the sin/cos pair)
      float inv_dim = __expf(-0.07195578415606394f * (float)(d0 / 2 + p));
      float ang = (float)l * inv_dim;
      float sv = __sinf(ang);
      float cv = __cosf(ang);
      pe_out[2 * p]     = f2bf(xv[2 * p] + sv);
      pe_out[2 * p + 1] = f2bf(xv[2 * p + 1] + cv);
      xb_out[2 * p]     = f2bf(xv[2 * p]);
      xb_out[2 * p + 1] = f2bf(xv[2 * p + 1]);
    }
    *(int4*)(xpe + (size_t)t * ND + d0) = *(int4*)pe_out;
    *(int4*)(xb  + (size_t)t * ND + d0) = *(int4*)xb_out;
  } else {
    __shared__ float tile[64 * 65];
    int widx = bid - (NTOK * ND) / (256 * 8);   // 0..95
    int m = widx >> 5;                          // matrix 0..2
    int tl = widx & 31;                         // 0..31
    int kt = tl & 3;                            // k-tile (256/64)
    int nt = tl >> 2;                           // n-tile (512/64)
    const float* W = (m == 0) ? Wq : (m == 1) ? Wk : Wv;
    unsigned short* Wt = (m == 0) ? wqt : (m == 1) ? wkt : wvt;
    int c = tid & 63, rb = tid >> 6;
#pragma unroll
    for (int i = 0; i < 16; ++i) {
      int r = i * 4 + rb;   // k_local
      tile[r * 65 + c] = W[(kt * 64 + r) * NC + nt * 64 + c];
    }
    __syncthreads();
#pragma unroll
    for (int i = 0; i < 16; ++i) {
      int n_local = i * 4 + rb, k_local = c;
      Wt[(nt * 64 + n_local) * ND + kt * 64 + k_local] =
          f2bf(tile[k_local * 65 + n_local]);
    }
  }
}

// ---------------------------------------------------------------------------
// Fused QKV projection GEMM: grid.z in {0:q, 1:k, 2:v}
// Out = (X[8192x256] * W[256x512] + bias_per_head) * scale
// MFMA 16x16x32 bf16, tile 128(M) x 64(N), BK=64, 4 waves.
// Register double-buffer with NAMED int4 temporaries (no lambda, no array:
// round-6 lambda capture put the buffers in scratch -> 237MB WRITE_SIZE).
// z<2: Out[(b,h,l,d)]   z==2 (v): Out[(b,h,d,l)] (transposed for attention)
// q additionally folds attention scale AND log2(e) (softmax in exp2 domain).
// ---------------------------------------------------------------------------
__global__ __launch_bounds__(256) void gemm_qkv_kernel(
    const unsigned short* __restrict__ xpe, const unsigned short* __restrict__ xb,
    const unsigned short* __restrict__ wqt, const unsigned short* __restrict__ wkt,
    const unsigned short* __restrict__ wvt,
    const float* __restrict__ bq, const float* __restrict__ bk,
    const float* __restrict__ bv,
    unsigned short* __restrict__ qg, unsigned short* __restrict__ kg,
    unsigned short* __restrict__ vg) {
  __shared__ unsigned short As[128 * 72];
  __shared__ unsigned short Bs[64 * 72];

  const int z = blockIdx.z;
  const unsigned short* X  = (z == 2) ? xb : xpe;
  const unsigned short* Wt = (z == 0) ? wqt : (z == 1) ? wkt : wvt;
  const float* bias        = (z == 0) ? bq  : (z == 1) ? bk  : bv;
  unsigned short* Out      = (z == 0) ? qg  : (z == 1) ? kg  : vg;
  // q: 1/sqrt(64) * log2(e)  (exp2-domain softmax)
  const float scale        = (z == 0) ? 0.18033688011112042f : 1.0f;

  const int nt = blockIdx.x;     // 0..7   N tile
  const int mt = blockIdx.y;     // 0..63  M tile
  const int tid = threadIdx.x;
  const int w = tid >> 6;
  const int lane = tid & 63;
  const int lg = lane >> 4;      // 0..3
  const int lr = lane & 15;      // 0..15

  // Per-thread staging geometry: slot i covers row r0+i*32, same 16B column.
  const int r0 = tid >> 3;
  const int c8o = (tid & 7) * 8;
  const unsigned short* Abase = X + (size_t)(mt * 128 + r0) * ND + c8o;
  const unsigned short* Bbase = Wt + (size_t)(nt * 64 + r0) * ND + c8o;
  unsigned short* Adst = As + r0 * 72 + c8o;
  unsigned short* Bdst = Bs + r0 * 72 + c8o;

  f32x4 acc[2][4] = {};
  int4 a0, a1, a2, a3, b0, b1;

#define GLOADS(kb)                                              \
  a0 = *(const int4*)(Abase + (kb) * 64);                       \
  a1 = *(const int4*)(Abase + (kb) * 64 + 32 * ND);             \
  a2 = *(const int4*)(Abase + (kb) * 64 + 64 * ND);             \
  a3 = *(const int4*)(Abase + (kb) * 64 + 96 * ND);             \
  b0 = *(const int4*)(Bbase + (kb) * 64);                       \
  b1 = *(const int4*)(Bbase + (kb) * 64 + 32 * ND);

  GLOADS(0)
#pragma unroll
  for (int kb = 0; kb < 4; ++kb) {
    if (kb) __syncthreads();
    *(int4*)(Adst)           = a0;
    *(int4*)(Adst + 32 * 72) = a1;
    *(int4*)(Adst + 64 * 72) = a2;
    *(int4*)(Adst + 96 * 72) = a3;
    *(int4*)(Bdst)           = b0;
    *(int4*)(Bdst + 32 * 72) = b1;
    if (kb == 0) { GLOADS(1) }
    else if (kb == 1) { GLOADS(2) }
    else if (kb == 2) { GLOADS(3) }
    __syncthreads();

#pragma unroll
    for (int kk = 0; kk < 2; ++kk) {
      bf16x8v a[2], b[4];
#pragma unroll
      for (int mi = 0; mi < 2; ++mi)
        a[mi] = *(const bf16x8v*)(As + (w * 32 + mi * 16 + lr) * 72 + kk * 32 + lg * 8);
#pragma unroll
      for (int nb = 0; nb < 4; ++nb)
        b[nb] = *(const bf16x8v*)(Bs + (nb * 16 + lr) * 72 + kk * 32 + lg * 8);
#pragma unroll
      for (int mi = 0; mi < 2; ++mi)
#pragma unroll
        for (int nb = 0; nb < 4; ++nb)
          acc[mi][nb] = __builtin_amdgcn_mfma_f32_16x16x32_bf16(
              a[mi], b[nb], acc[mi][nb], 0, 0, 0);
    }
  }
#undef GLOADS

  // C row = (lane>>4)*4 + j, col = lane&15  [HW-verified layout]
#pragma unroll
  for (int mi = 0; mi < 2; ++mi) {
#pragma unroll
    for (int nb = 0; nb < 4; ++nb) {
#pragma unroll
      for (int j = 0; j < 4; ++j) {
        int r = mt * 128 + w * 32 + mi * 16 + lg * 4 + j;   // token index
        int c = nt * 64 + nb * 16 + lr;                     // column in [0,512)
        int bb = r >> 10, lpos = r & (NL - 1);
        int h = c >> 6, dd = c & 63;
        float val = (acc[mi][nb][j] + bias[h]) * scale;
        if (z < 2)
          Out[((bb * NH + h) * NL + lpos) * NHD + dd] = f2bf(val);
        else
          Out[((bb * NH + h) * NHD + dd) * NL + lpos] = f2bf(val);
      }
    }
  }
}

// ---------------------------------------------------------------------------
// Flash attention, swapped-operand + exp2-domain + defer-max + async staging.
// grid (16 q-tiles, 64 bh), 4 waves; each wave owns 16 q-rows.
//   S^T = mfma(kf, qf): lane(lr,lg) holds S[q=lr][k=16nb+4lg+j] (log2 units)
//   O^T = mfma(vf, pf): lane(lr,lg) holds O[d=16db+4lg+j][q=lr]
// K/V double-buffered through NAMED int4 temporaries (registers, not scratch).
// Defer-max (THR=8 in log2 units -> P<=256, f32-safe).
// ---------------------------------------------------------------------------
__global__ __launch_bounds__(256) void attn_kernel(
    const unsigned short* __restrict__ Q,
    const unsigned short* __restrict__ K,
    const unsigned short* __restrict__ Vt,
    float* __restrict__ Out) {
  __shared__ unsigned short Ks[64 * 72];
  __shared__ unsigned short Vs[64 * 72];
  __shared__ unsigned short Ps[64 * 72];

  const int qt = blockIdx.x;   // 0..15
  const int bh = blockIdx.y;   // 0..63
  const int bb = bh >> 3, h = bh & 7;
  const int tid = threadIdx.x;
  const int w = tid >> 6;
  const int lane = tid & 63;
  const int lg = lane >> 4, lr = lane & 15;
  const int qrow0 = qt * 64 + w * 16;

  // Q B-fragment: row = lr, k-slice = lg*8 within each 32-block
  bf16x8v qf[2];
#pragma unroll
  for (int kk = 0; kk < 2; ++kk)
    qf[kk] = *(const bf16x8v*)(Q + ((size_t)bh * NL + qrow0 + lr) * NHD + kk * 32 + lg * 8);

  // Per-thread staging geometry: rows r0 and r0+32, fixed 16B column c8o.
  const int r0 = tid >> 3;
  const int c8o = (tid & 7) * 8;
  const unsigned short* kp0 = K + (size_t)bh * NL * NHD + r0 * NHD + c8o;   // +kv*64*NHD
  const unsigned short* vp0 = Vt + ((size_t)bh * NHD + r0) * NL + c8o;      // +kv*64
  unsigned short* kdst = Ks + r0 * 72 + c8o;
  unsigned short* vdst = Vs + r0 * 72 + c8o;

  float m_ = -1e30f, lsum = 0.0f;
  f32x4 o[4] = {};
  int4 ka, kc, va, vc;

#define KVLOADS(kv)                                             \
  ka = *(const int4*)(kp0 + (kv) * 64 * NHD);                   \
  kc = *(const int4*)(kp0 + (kv) * 64 * NHD + 32 * NHD);        \
  va = *(const int4*)(vp0 + (kv) * 64);                         \
  vc = *(const int4*)(vp0 + (kv) * 64 + 32 * NL);

  KVLOADS(0)
  for (int kv = 0; kv < 16; ++kv) {
    if (kv) __syncthreads();          // all waves done with previous tile
    *(int4*)(kdst)           = ka;
    *(int4*)(kdst + 32 * 72) = kc;
    *(int4*)(vdst)           = va;
    *(int4*)(vdst + 32 * 72) = vc;
    if (kv < 15) { KVLOADS(kv + 1) }  // next tile loads fly during compute
    __syncthreads();

    // S^T = K * Q^T (log2 units; scale*log2e folded into Q)
    f32x4 s[4] = {};
#pragma unroll
    for (int kk = 0; kk < 2; ++kk) {
#pragma unroll
      for (int nb = 0; nb < 4; ++nb) {
        bf16x8v kf = *(const bf16x8v*)(Ks + (nb * 16 + lr) * 72 + kk * 32 + lg * 8);
        s[nb] = __builtin_amdgcn_mfma_f32_16x16x32_bf16(kf, qf[kk], s[nb], 0, 0, 0);
      }
    }

    // Online softmax, exp2 domain, defer-max (wave-uniform rescale decision)
    float tm = s[0][0];
#pragma unroll
    for (int nb = 0; nb < 4; ++nb)
#pragma unroll
      for (int j = 0; j < 4; ++j) tm = fmaxf(tm, s[nb][j]);
    tm = fmaxf(tm, __shfl_xor(tm, 16, 64));
    tm = fmaxf(tm, __shfl_xor(tm, 32, 64));
    if (__any(tm > m_ + 8.0f)) {
      float nm = fmaxf(m_, tm);
      float corr = exp2f(m_ - nm);
      m_ = nm;
      lsum *= corr;
#pragma unroll
      for (int db = 0; db < 4; ++db)
#pragma unroll
        for (int j = 0; j < 4; ++j) o[db][j] *= corr;
    }
    float ts = 0.0f;
#pragma unroll
    for (int nb = 0; nb < 4; ++nb)
#pragma unroll
      for (int j = 0; j < 4; ++j) {
        float p = exp2f(s[nb][j] - m_);
        s[nb][j] = p;
        ts += p;
      }
    ts += __shfl_xor(ts, 16, 64);
    ts += __shfl_xor(ts, 32, 64);
    lsum += ts;

    // P row q=lr -> LDS packed u32 (wave-private rows; no barrier needed)
#pragma unroll
    for (int nb = 0; nb < 4; ++nb)
#pragma unroll
      for (int hh = 0; hh < 2; ++hh)
        *(unsigned*)(Ps + (w * 16 + lr) * 72 + nb * 16 + lg * 4 + 2 * hh) =
            pack_bf16x2(s[nb][2 * hh], s[nb][2 * hh + 1]);

    // O^T += V^T * P^T
#pragma unroll
    for (int kk = 0; kk < 2; ++kk) {
      bf16x8v pf = *(const bf16x8v*)(Ps + (w * 16 + lr) * 72 + kk * 32 + lg * 8);
#pragma unroll
      for (int db = 0; db < 4; ++db) {
        bf16x8v vf = *(const bf16x8v*)(Vs + (db * 16 + lr) * 72 + kk * 32 + lg * 8);
        o[db] = __builtin_amdgcn_mfma_f32_16x16x32_bf16(vf, pf, o[db], 0, 0, 0);
      }
    }
  }
#undef KVLOADS

  // Normalize (scalar per lane) and write out[B, L, 512] f32 as float4s
  float inv = 1.0f / lsum;
  int q = qrow0 + lr;
#pragma unroll
  for (int db = 0; db < 4; ++db) {
    f32x4 ov;
#pragma unroll
    for (int j = 0; j < 4; ++j) ov[j] = o[db][j] * inv;
    *(f32x4*)(Out + (size_t)(bb * NL + q) * NC + h * NHD + db * 16 + lg * 4) = ov;
  }
}

// ---------------------------------------------------------------------------
extern "C" void kernel_launch(void* const* d_in, const int* in_sizes, int n_in,
                              void* d_out, int out_size, void* d_ws, size_t ws_size,
                              hipStream_t stream) {
  const float* x  = (const float*)d_in[0];
  const float* Wq = (const float*)d_in[1];
  const float* bq = (const float*)d_in[2];
  const float* Wk = (const float*)d_in[3];
  const float* bk = (const float*)d_in[4];
  const float* Wv = (const float*)d_in[5];
  const float* bv = (const float*)d_in[6];
  float* out = (float*)d_out;

  // Workspace layout (all bf16 stored as ushort)
  unsigned short* xpe = (unsigned short*)d_ws;        // 2M elems
  unsigned short* xb  = xpe + (size_t)NTOK * ND;      // 2M
  unsigned short* wqt = xb  + (size_t)NTOK * ND;      // 128K
  unsigned short* wkt = wqt + (size_t)ND * NC;
  unsigned short* wvt = wkt + (size_t)ND * NC;
  unsigned short* qg  = wvt + (size_t)ND * NC;        // 512K each
  unsigned short* kg  = qg  + (size_t)NB * NH * NL * NHD;
  unsigned short* vg  = kg  + (size_t)NB * NH * NL * NHD;

  int prep_blocks = (NTOK * ND) / (256 * 8) + 96;   // 1024 + 96
  prep_kernel<<<prep_blocks, 256, 0, stream>>>(x, Wq, Wk, Wv, xpe, xb, wqt, wkt, wvt);

  gemm_qkv_kernel<<<dim3(8, 64, 3), 256, 0, stream>>>(
      xpe, xb, wqt, wkt, wvt, bq, bk, bv, qg, kg, vg);

  attn_kernel<<<dim3(16, 64), 256, 0, stream>>>(qg, kg, vg, out);
}

// Round 10
// 137.905 us; speedup vs baseline: 1.5984x; 1.0316x over previous
//
#include <hip/hip_runtime.h>
#include <hip/hip_bf16.h>

// Problem constants
#define NB   8      // batch
#define NL   1024   // sequence length
#define ND   256    // model dim
#define NH   8      // heads
#define NHD  64     // head dim
#define NC   512    // NH*NHD
#define NTOK (NB*NL) // 8192

typedef __bf16 bf16x8v __attribute__((ext_vector_type(8)));
typedef float f32x4 __attribute__((ext_vector_type(4)));

__device__ __forceinline__ unsigned short f2bf(float f) {
  unsigned u = __float_as_uint(f);
  unsigned r = (u + 0x7fffu + ((u >> 16) & 1u)) >> 16;
  return (unsigned short)r;
}

// pack two f32 -> bf16x2 (elem0 in low 16 bits)
__device__ __forceinline__ unsigned pack_bf16x2(float lo, float hi) {
  __hip_bfloat162 h2 = __float22bfloat162_rn(make_float2(lo, hi));
  union { __hip_bfloat162 h; unsigned u; } cvt;
  cvt.h = h2;
  return cvt.u;
}

// ---------------------------------------------------------------------------
// Fused prep.
// Blocks [0,1024): 8 elems/thread: xpe = bf16(x + PE), xb = bf16(x).
// Blocks [1024,1120): LDS-tiled 64x64 transpose: Wt[n][k] = bf16(W[k][n]).
// ---------------------------------------------------------------------------
__global__ __launch_bounds__(256) void prep_kernel(
    const float* __restrict__ x,
    const float* __restrict__ Wq, const float* __restrict__ Wk,
    const float* __restrict__ Wv,
    unsigned short* __restrict__ xpe, unsigned short* __restrict__ xb,
    unsigned short* __restrict__ wqt, unsigned short* __restrict__ wkt,
    unsigned short* __restrict__ wvt) {
  const int bid = blockIdx.x;
  const int tid = threadIdx.x;
  if (bid < (NTOK * ND) / (256 * 8)) {
    int idx = bid * 256 + tid;        // 0 .. 262143, 8 elems each
    int d0 = (idx & 31) * 8;          // 32 chunks of 8 dims per token
    int t = idx >> 5;                 // token
    int l = t & (NL - 1);
    float4 xa = *(const float4*)(x + (size_t)t * ND + d0);
    float4 xc = *(const float4*)(x + (size_t)t * ND + d0 + 4);
    float xv[8] = {xa.x, xa.y, xa.z, xa.w, xc.x, xc.y, xc.z, xc.w};
    unsigned short pe_out[8], xb_out[8];
#pragma unroll
    for (int p = 0; p < 4; ++p) {
      // exponent index = d>>1 = d0/2 + p  (shared by the sin/cos pair)
      float inv_dim = __expf(-0.07195578415606394f * (float)(d0 / 2 + p));
      float ang = (float)l * inv_dim;
      float sv = __sinf(ang);
      float cv = __cosf(ang);
      pe_out[2 * p]     = f2bf(xv[2 * p] + sv);
      pe_out[2 * p + 1] = f2bf(xv[2 * p + 1] + cv);
      xb_out[2 * p]     = f2bf(xv[2 * p]);
      xb_out[2 * p + 1] = f2bf(xv[2 * p + 1]);
    }
    *(int4*)(xpe + (size_t)t * ND + d0) = *(int4*)pe_out;
    *(int4*)(xb  + (size_t)t * ND + d0) = *(int4*)xb_out;
  } else {
    __shared__ float tile[64 * 65];
    int widx = bid - (NTOK * ND) / (256 * 8);   // 0..95
    int m = widx >> 5;                          // matrix 0..2
    int tl = widx & 31;                         // 0..31
    int kt = tl & 3;                            // k-tile (256/64)
    int nt = tl >> 2;                           // n-tile (512/64)
    const float* W = (m == 0) ? Wq : (m == 1) ? Wk : Wv;
    unsigned short* Wt = (m == 0) ? wqt : (m == 1) ? wkt : wvt;
    int c = tid & 63, rb = tid >> 6;
#pragma unroll
    for (int i = 0; i < 16; ++i) {
      int r = i * 4 + rb;   // k_local
      tile[r * 65 + c] = W[(kt * 64 + r) * NC + nt * 64 + c];
    }
    __syncthreads();
#pragma unroll
    for (int i = 0; i < 16; ++i) {
      int n_local = i * 4 + rb, k_local = c;
      Wt[(nt * 64 + n_local) * ND + kt * 64 + k_local] =
          f2bf(tile[k_local * 65 + n_local]);
    }
  }
}

// ---------------------------------------------------------------------------
// Fused QKV projection GEMM: grid (4 nt, 64 mt, 3 z)
// Out = (X[8192x256] * W[256x512] + bias_per_head) * scale
// Tile 128(M) x 128(N), BK=64, 4 waves each computing a 64x64 sub-tile
// (2x2 wave grid). 32 MFMA per barrier window, MFMA:ds_read = 2:1.
// Register double-buffer with NAMED int4 temporaries (scratch-safe).
// z<2: Out[(b,h,l,d)]   z==2 (v): Out[(b,h,d,l)] (transposed for attention)
// q folds attention scale AND log2(e) (softmax in exp2 domain).
// ---------------------------------------------------------------------------
__global__ __launch_bounds__(256) void gemm_qkv_kernel(
    const unsigned short* __restrict__ xpe, const unsigned short* __restrict__ xb,
    const unsigned short* __restrict__ wqt, const unsigned short* __restrict__ wkt,
    const unsigned short* __restrict__ wvt,
    const float* __restrict__ bq, const float* __restrict__ bk,
    const float* __restrict__ bv,
    unsigned short* __restrict__ qg, unsigned short* __restrict__ kg,
    unsigned short* __restrict__ vg) {
  __shared__ unsigned short As[128 * 72];
  __shared__ unsigned short Bs[128 * 72];

  const int z = blockIdx.z;
  const unsigned short* X  = (z == 2) ? xb : xpe;
  const unsigned short* Wt = (z == 0) ? wqt : (z == 1) ? wkt : wvt;
  const float* bias        = (z == 0) ? bq  : (z == 1) ? bk  : bv;
  unsigned short* Out      = (z == 0) ? qg  : (z == 1) ? kg  : vg;
  // q: 1/sqrt(64) * log2(e)  (exp2-domain softmax)
  const float scale        = (z == 0) ? 0.18033688011112042f : 1.0f;

  const int nt = blockIdx.x;     // 0..3   N tile (128 cols)
  const int mt = blockIdx.y;     // 0..63  M tile (128 rows)
  const int tid = threadIdx.x;
  const int w = tid >> 6;
  const int wm = w >> 1, wn = w & 1;   // 2x2 wave grid, 64x64 each
  const int lane = tid & 63;
  const int lg = lane >> 4;      // 0..3
  const int lr = lane & 15;      // 0..15

  // Per-thread staging geometry: rows r0 + {0,32,64,96}, fixed 16B column.
  const int r0 = tid >> 3;                 // 0..31
  const int c8o = (tid & 7) * 8;
  const unsigned short* Abase = X + (size_t)(mt * 128 + r0) * ND + c8o;
  const unsigned short* Bbase = Wt + (size_t)(nt * 128 + r0) * ND + c8o;
  unsigned short* Adst = As + r0 * 72 + c8o;
  unsigned short* Bdst = Bs + r0 * 72 + c8o;

  f32x4 acc[4][4] = {};
  int4 a0, a1, a2, a3, b0, b1, b2, b3;

#define GLOADS(kb)                                              \
  a0 = *(const int4*)(Abase + (kb) * 64);                       \
  a1 = *(const int4*)(Abase + (kb) * 64 + 32 * ND);             \
  a2 = *(const int4*)(Abase + (kb) * 64 + 64 * ND);             \
  a3 = *(const int4*)(Abase + (kb) * 64 + 96 * ND);             \
  b0 = *(const int4*)(Bbase + (kb) * 64);                       \
  b1 = *(const int4*)(Bbase + (kb) * 64 + 32 * ND);             \
  b2 = *(const int4*)(Bbase + (kb) * 64 + 64 * ND);             \
  b3 = *(const int4*)(Bbase + (kb) * 64 + 96 * ND);

  GLOADS(0)
#pragma unroll
  for (int kb = 0; kb < 4; ++kb) {
    if (kb) __syncthreads();
    *(int4*)(Adst)           = a0;
    *(int4*)(Adst + 32 * 72) = a1;
    *(int4*)(Adst + 64 * 72) = a2;
    *(int4*)(Adst + 96 * 72) = a3;
    *(int4*)(Bdst)           = b0;
    *(int4*)(Bdst + 32 * 72) = b1;
    *(int4*)(Bdst + 64 * 72) = b2;
    *(int4*)(Bdst + 96 * 72) = b3;
    if (kb == 0) { GLOADS(1) }
    else if (kb == 1) { GLOADS(2) }
    else if (kb == 2) { GLOADS(3) }
    __syncthreads();

#pragma unroll
    for (int kk = 0; kk < 2; ++kk) {
      bf16x8v a[4], b[4];
#pragma unroll
      for (int mi = 0; mi < 4; ++mi)
        a[mi] = *(const bf16x8v*)(As + (wm * 64 + mi * 16 + lr) * 72 + kk * 32 + lg * 8);
#pragma unroll
      for (int nj = 0; nj < 4; ++nj)
        b[nj] = *(const bf16x8v*)(Bs + (wn * 64 + nj * 16 + lr) * 72 + kk * 32 + lg * 8);
#pragma unroll
      for (int mi = 0; mi < 4; ++mi)
#pragma unroll
        for (int nj = 0; nj < 4; ++nj)
          acc[mi][nj] = __builtin_amdgcn_mfma_f32_16x16x32_bf16(
              a[mi], b[nj], acc[mi][nj], 0, 0, 0);
    }
  }
#undef GLOADS

  // C row = (lane>>4)*4 + j, col = lane&15  [HW-verified layout]
  // head h = c>>6 = nt*2 + wn  (wave-uniform; nj*16+lr < 64)
  const float bval = bias[nt * 2 + wn];
  const int h = nt * 2 + wn;
#pragma unroll
  for (int mi = 0; mi < 4; ++mi) {
#pragma unroll
    for (int nj = 0; nj < 4; ++nj) {
#pragma unroll
      for (int j = 0; j < 4; ++j) {
        int r = mt * 128 + wm * 64 + mi * 16 + lg * 4 + j;   // token index
        int dd = nj * 16 + lr;                               // dim within head
        int bb = r >> 10, lpos = r & (NL - 1);
        float val = (acc[mi][nj][j] + bval) * scale;
        if (z < 2)
          Out[((bb * NH + h) * NL + lpos) * NHD + dd] = f2bf(val);
        else
          Out[((bb * NH + h) * NHD + dd) * NL + lpos] = f2bf(val);
      }
    }
  }
}

// ---------------------------------------------------------------------------
// Flash attention, swapped-operand + exp2-domain + defer-max + async staging.
// grid (16 q-tiles, 64 bh), 4 waves; each wave owns 16 q-rows.
//   S^T = mfma(kf, qf): lane(lr,lg) holds S[q=lr][k=16nb+4lg+j] (log2 units)
//   O^T = mfma(vf, pf): lane(lr,lg) holds O[d=16db+4lg+j][q=lr]
// K/V double-buffered through NAMED int4 temporaries (registers, not scratch).
// Tree-structured max/sum reductions (depth 4, v_max3-fusable); s_setprio
// around MFMA clusters (T5, attn-measured +4-7%).
// ---------------------------------------------------------------------------
__global__ __launch_bounds__(256) void attn_kernel(
    const unsigned short* __restrict__ Q,
    const unsigned short* __restrict__ K,
    const unsigned short* __restrict__ Vt,
    float* __restrict__ Out) {
  __shared__ unsigned short Ks[64 * 72];
  __shared__ unsigned short Vs[64 * 72];
  __shared__ unsigned short Ps[64 * 72];

  const int qt = blockIdx.x;   // 0..15
  const int bh = blockIdx.y;   // 0..63
  const int bb = bh >> 3, h = bh & 7;
  const int tid = threadIdx.x;
  const int w = tid >> 6;
  const int lane = tid & 63;
  const int lg = lane >> 4, lr = lane & 15;
  const int qrow0 = qt * 64 + w * 16;

  // Q B-fragment: row = lr, k-slice = lg*8 within each 32-block
  bf16x8v qf[2];
#pragma unroll
  for (int kk = 0; kk < 2; ++kk)
    qf[kk] = *(const bf16x8v*)(Q + ((size_t)bh * NL + qrow0 + lr) * NHD + kk * 32 + lg * 8);

  // Per-thread staging geometry: rows r0 and r0+32, fixed 16B column c8o.
  const int r0 = tid >> 3;
  const int c8o = (tid & 7) * 8;
  const unsigned short* kp0 = K + (size_t)bh * NL * NHD + r0 * NHD + c8o;   // +kv*64*NHD
  const unsigned short* vp0 = Vt + ((size_t)bh * NHD + r0) * NL + c8o;      // +kv*64
  unsigned short* kdst = Ks + r0 * 72 + c8o;
  unsigned short* vdst = Vs + r0 * 72 + c8o;

  float m_ = -1e30f, lsum = 0.0f;
  f32x4 o[4] = {};
  int4 ka, kc, va, vc;

#define KVLOADS(kv)                                             \
  ka = *(const int4*)(kp0 + (kv) * 64 * NHD);                   \
  kc = *(const int4*)(kp0 + (kv) * 64 * NHD + 32 * NHD);        \
  va = *(const int4*)(vp0 + (kv) * 64);                         \
  vc = *(const int4*)(vp0 + (kv) * 64 + 32 * NL);

  KVLOADS(0)
  for (int kv = 0; kv < 16; ++kv) {
    if (kv) __syncthreads();          // all waves done with previous tile
    *(int4*)(kdst)           = ka;
    *(int4*)(kdst + 32 * 72) = kc;
    *(int4*)(vdst)           = va;
    *(int4*)(vdst + 32 * 72) = vc;
    if (kv < 15) { KVLOADS(kv + 1) }  // next tile loads fly during compute
    __syncthreads();

    // S^T = K * Q^T (log2 units; scale*log2e folded into Q)
    f32x4 s[4] = {};
    __builtin_amdgcn_s_setprio(1);
#pragma unroll
    for (int kk = 0; kk < 2; ++kk) {
#pragma unroll
      for (int nb = 0; nb < 4; ++nb) {
        bf16x8v kf = *(const bf16x8v*)(Ks + (nb * 16 + lr) * 72 + kk * 32 + lg * 8);
        s[nb] = __builtin_amdgcn_mfma_f32_16x16x32_bf16(kf, qf[kk], s[nb], 0, 0, 0);
      }
    }
    __builtin_amdgcn_s_setprio(0);

    // Online softmax, exp2 domain, defer-max (wave-uniform rescale decision)
    // Tree-structured 16-value max (depth 4, v_max3-fusable)
    float tm;
    {
      float a0 = fmaxf(s[0][0], s[0][1]), a1 = fmaxf(s[0][2], s[0][3]);
      float a2 = fmaxf(s[1][0], s[1][1]), a3 = fmaxf(s[1][2], s[1][3]);
      float a4 = fmaxf(s[2][0], s[2][1]), a5 = fmaxf(s[2][2], s[2][3]);
      float a6 = fmaxf(s[3][0], s[3][1]), a7 = fmaxf(s[3][2], s[3][3]);
      float c0 = fmaxf(fmaxf(a0, a1), fmaxf(a2, a3));
      float c1 = fmaxf(fmaxf(a4, a5), fmaxf(a6, a7));
      tm = fmaxf(c0, c1);
    }
    tm = fmaxf(tm, __shfl_xor(tm, 16, 64));
    tm = fmaxf(tm, __shfl_xor(tm, 32, 64));
    if (__any(tm > m_ + 8.0f)) {
      float nm = fmaxf(m_, tm);
      float corr = exp2f(m_ - nm);
      m_ = nm;
      lsum *= corr;
#pragma unroll
      for (int db = 0; db < 4; ++db)
#pragma unroll
        for (int j = 0; j < 4; ++j) o[db][j] *= corr;
    }
#pragma unroll
    for (int nb = 0; nb < 4; ++nb)
#pragma unroll
      for (int j = 0; j < 4; ++j)
        s[nb][j] = exp2f(s[nb][j] - m_);
    float ts;
    {
      float a0 = s[0][0] + s[0][1], a1 = s[0][2] + s[0][3];
      float a2 = s[1][0] + s[1][1], a3 = s[1][2] + s[1][3];
      float a4 = s[2][0] + s[2][1], a5 = s[2][2] + s[2][3];
      float a6 = s[3][0] + s[3][1], a7 = s[3][2] + s[3][3];
      ts = ((a0 + a1) + (a2 + a3)) + ((a4 + a5) + (a6 + a7));
    }
    ts += __shfl_xor(ts, 16, 64);
    ts += __shfl_xor(ts, 32, 64);
    lsum += ts;

    // P row q=lr -> LDS packed u32 (wave-private rows; no barrier needed)
#pragma unroll
    for (int nb = 0; nb < 4; ++nb)
#pragma unroll
      for (int hh = 0; hh < 2; ++hh)
        *(unsigned*)(Ps + (w * 16 + lr) * 72 + nb * 16 + lg * 4 + 2 * hh) =
            pack_bf16x2(s[nb][2 * hh], s[nb][2 * hh + 1]);

    // O^T += V^T * P^T
    __builtin_amdgcn_s_setprio(1);
#pragma unroll
    for (int kk = 0; kk < 2; ++kk) {
      bf16x8v pf = *(const bf16x8v*)(Ps + (w * 16 + lr) * 72 + kk * 32 + lg * 8);
#pragma unroll
      for (int db = 0; db < 4; ++db) {
        bf16x8v vf = *(const bf16x8v*)(Vs + (db * 16 + lr) * 72 + kk * 32 + lg * 8);
        o[db] = __builtin_amdgcn_mfma_f32_16x16x32_bf16(vf, pf, o[db], 0, 0, 0);
      }
    }
    __builtin_amdgcn_s_setprio(0);
  }
#undef KVLOADS

  // Normalize (scalar per lane) and write out[B, L, 512] f32 as float4s
  float inv = 1.0f / lsum;
  int q = qrow0 + lr;
#pragma unroll
  for (int db = 0; db < 4; ++db) {
    f32x4 ov;
#pragma unroll
    for (int j = 0; j < 4; ++j) ov[j] = o[db][j] * inv;
    *(f32x4*)(Out + (size_t)(bb * NL + q) * NC + h * NHD + db * 16 + lg * 4) = ov;
  }
}

// ---------------------------------------------------------------------------
extern "C" void kernel_launch(void* const* d_in, const int* in_sizes, int n_in,
                              void* d_out, int out_size, void* d_ws, size_t ws_size,
                              hipStream_t stream) {
  const float* x  = (const float*)d_in[0];
  const float* Wq = (const float*)d_in[1];
  const float* bq = (const float*)d_in[2];
  const float* Wk = (const float*)d_in[3];
  const float* bk = (const float*)d_in[4];
  const float* Wv = (const float*)d_in[5];
  const float* bv = (const float*)d_in[6];
  float* out = (float*)d_out;

  // Workspace layout (all bf16 stored as ushort)
  unsigned short* xpe = (unsigned short*)d_ws;        // 2M elems
  unsigned short* xb  = xpe + (size_t)NTOK * ND;      // 2M
  unsigned short* wqt = xb  + (size_t)NTOK * ND;      // 128K
  unsigned short* wkt = wqt + (size_t)ND * NC;
  unsigned short* wvt = wkt + (size_t)ND * NC;
  unsigned short* qg  = wvt + (size_t)ND * NC;        // 512K each
  unsigned short* kg  = qg  + (size_t)NB * NH * NL * NHD;
  unsigned short* vg  = kg  + (size_t)NB * NH * NL * NHD;

  int prep_blocks = (NTOK * ND) / (256 * 8) + 96;   // 1024 + 96
  prep_kernel<<<prep_blocks, 256, 0, stream>>>(x, Wq, Wk, Wv, xpe, xb, wqt, wkt, wvt);

  gemm_qkv_kernel<<<dim3(4, 64, 3), 256, 0, stream>>>(
      xpe, xb, wqt, wkt, wvt, bq, bk, bv, qg, kg, vg);

  attn_kernel<<<dim3(16, 64), 256, 0, stream>>>(qg, kg, vg, out);
}

// Round 11
// 134.527 us; speedup vs baseline: 1.6385x; 1.0251x over previous
//
#include <hip/hip_runtime.h>
#include <hip/hip_bf16.h>

// Problem constants
#define NB   8      // batch
#define NL   1024   // sequence length
#define ND   256    // model dim
#define NH   8      // heads
#define NHD  64     // head dim
#define NC   512    // NH*NHD
#define NTOK (NB*NL) // 8192

typedef __bf16 bf16x8v __attribute__((ext_vector_type(8)));
typedef float f32x4 __attribute__((ext_vector_type(4)));

__device__ __forceinline__ unsigned short f2bf(float f) {
  unsigned u = __float_as_uint(f);
  unsigned r = (u + 0x7fffu + ((u >> 16) & 1u)) >> 16;
  return (unsigned short)r;
}

// pack two f32 -> bf16x2 (elem0 in low 16 bits), RNE
__device__ __forceinline__ unsigned pack_bf16x2(float lo, float hi) {
  __hip_bfloat162 h2 = __float22bfloat162_rn(make_float2(lo, hi));
  union { __hip_bfloat162 h; unsigned u; } cvt;
  cvt.h = h2;
  return cvt.u;
}

// ---------------------------------------------------------------------------
// Fused QKV projection GEMM (prep folded in): grid (4 nt, 64 mt, 3 z)
// Reads x f32 + W f32 directly. A-tile: bf16(x + PE) computed on the fly
// (PE skipped for z==2/v). B-tile: W transposed on the fly, k-pairs packed
// into b32 LDS writes. Tile 128x128, BK=64, 2x2 wave grid, acc[4][4].
// LDS slot-swizzle: 16B-slot s' = (s + key(row)) & 7 (A/K-style key = 2*(row&7),
// B key = (n>>3)&7) -- write and read sides use the same element mapping.
// z<2: Out[(b,h,l,d)]   z==2: Out[(b,h,d,l)] (transposed for attention)
// q folds attention scale AND log2(e) (softmax in exp2 domain).
// ---------------------------------------------------------------------------
__global__ __launch_bounds__(256) void gemm_qkv_fused_kernel(
    const float* __restrict__ x,
    const float* __restrict__ Wq, const float* __restrict__ Wk,
    const float* __restrict__ Wv,
    const float* __restrict__ bq, const float* __restrict__ bk,
    const float* __restrict__ bv,
    unsigned short* __restrict__ qg, unsigned short* __restrict__ kg,
    unsigned short* __restrict__ vg) {
  __shared__ unsigned short As[128 * 72];
  __shared__ unsigned short Bs[128 * 72];

  const int z = blockIdx.z;
  const float* Wsrc = (z == 0) ? Wq : (z == 1) ? Wk : Wv;
  const float* bias = (z == 0) ? bq : (z == 1) ? bk : bv;
  unsigned short* Out = (z == 0) ? qg : (z == 1) ? kg : vg;
  const float scale = (z == 0) ? 0.18033688011112042f : 1.0f;
  const bool addpe = (z < 2);

  const int nt = blockIdx.x;     // 0..3   N tile (128 cols)
  const int mt = blockIdx.y;     // 0..63  M tile (128 rows)
  const int tid = threadIdx.x;
  const int w = tid >> 6;
  const int wm = w >> 1, wn = w & 1;
  const int lane = tid & 63;
  const int lg = lane >> 4, lr = lane & 15;

  // A staging geometry: rows r0+32i, 8 k-elems at c8*8. Swizzled base
  // (row&7 == r0&7 for all four rows since 32 = 0 mod 8).
  const int r0 = tid >> 3, c8 = tid & 7;
  unsigned short* Adst = As + r0 * 72 + 8 * ((c8 + 2 * (r0 & 7)) & 7);
  const float* xbase = x + (size_t)(mt * 128 + r0) * ND + c8 * 8;
  // B staging geometry: thread covers k-pairs kp0,kp0+16 x 8 n at no*8.
  const int no = tid & 15, kp0 = tid >> 4;

  f32x4 acc[4][4] = {};

  for (int kb = 0; kb < 4; ++kb) {
    if (kb) __syncthreads();
    // ---- A staging: bf16(x + PE) ----
    float i0 = 0.f, i1 = 0.f, i2 = 0.f, i3 = 0.f;
    if (addpe) {
      int dh = kb * 32 + c8 * 4;   // d>>1 for this thread's 4 sin/cos pairs
      i0 = __expf(-0.07195578415606394f * (float)(dh));
      i1 = __expf(-0.07195578415606394f * (float)(dh + 1));
      i2 = __expf(-0.07195578415606394f * (float)(dh + 2));
      i3 = __expf(-0.07195578415606394f * (float)(dh + 3));
    }
#pragma unroll
    for (int i = 0; i < 4; ++i) {
      int row = r0 + 32 * i;
      f32x4 xa = *(const f32x4*)(xbase + (size_t)(32 * i) * ND + kb * 64);
      f32x4 xc = *(const f32x4*)(xbase + (size_t)(32 * i) * ND + kb * 64 + 4);
      unsigned p0, p1, p2, p3;
      if (addpe) {
        float l = (float)((mt * 128 + row) & (NL - 1));
        float a0 = l * i0, a1 = l * i1, a2 = l * i2, a3 = l * i3;
        p0 = pack_bf16x2(xa[0] + __sinf(a0), xa[1] + __cosf(a0));
        p1 = pack_bf16x2(xa[2] + __sinf(a1), xa[3] + __cosf(a1));
        p2 = pack_bf16x2(xc[0] + __sinf(a2), xc[1] + __cosf(a2));
        p3 = pack_bf16x2(xc[2] + __sinf(a3), xc[3] + __cosf(a3));
      } else {
        p0 = pack_bf16x2(xa[0], xa[1]);
        p1 = pack_bf16x2(xa[2], xa[3]);
        p2 = pack_bf16x2(xc[0], xc[1]);
        p3 = pack_bf16x2(xc[2], xc[3]);
      }
      int4 pv; pv.x = (int)p0; pv.y = (int)p1; pv.z = (int)p2; pv.w = (int)p3;
      *(int4*)(Adst + (size_t)(32 * i) * 72) = pv;
    }
    // ---- B staging: transpose W f32 -> Bs[n][k] bf16 (k-pairs, b32) ----
#pragma unroll
    for (int u = 0; u < 2; ++u) {
      int kp = kp0 + 16 * u;                 // k-pair index 0..31
      int krow = kb * 64 + 2 * kp;
      const float* wr0 = Wsrc + (size_t)krow * NC + nt * 128 + no * 8;
      const float* wr1 = wr0 + NC;
      f32x4 w0a = *(const f32x4*)(wr0);
      f32x4 w0b = *(const f32x4*)(wr0 + 4);
      f32x4 w1a = *(const f32x4*)(wr1);
      f32x4 w1b = *(const f32x4*)(wr1 + 4);
#pragma unroll
      for (int e = 0; e < 8; ++e) {
        float lo = (e < 4) ? w0a[e] : w0b[e - 4];
        float hi = (e < 4) ? w1a[e] : w1b[e - 4];
        int n = no * 8 + e;
        *(unsigned*)(Bs + n * 72 + 8 * (((kp >> 2) + (no & 7)) & 7) +
                     (kp & 3) * 2) = pack_bf16x2(lo, hi);
      }
    }
    __syncthreads();

    // ---- MFMA (swizzled LDS reads) ----
#pragma unroll
    for (int kk = 0; kk < 2; ++kk) {
      bf16x8v a[4], b[4];
#pragma unroll
      for (int mi = 0; mi < 4; ++mi) {
        int row = wm * 64 + mi * 16 + lr;
        a[mi] = *(const bf16x8v*)(As + row * 72 +
                                  8 * ((4 * kk + lg + 2 * (row & 7)) & 7));
      }
#pragma unroll
      for (int nj = 0; nj < 4; ++nj) {
        int n = wn * 64 + nj * 16 + lr;
        b[nj] = *(const bf16x8v*)(Bs + n * 72 +
                                  8 * ((4 * kk + lg + ((n >> 3) & 7)) & 7));
      }
#pragma unroll
      for (int mi = 0; mi < 4; ++mi)
#pragma unroll
        for (int nj = 0; nj < 4; ++nj)
          acc[mi][nj] = __builtin_amdgcn_mfma_f32_16x16x32_bf16(
              a[mi], b[nj], acc[mi][nj], 0, 0, 0);
    }
  }

  // C row = (lane>>4)*4 + j, col = lane&15  [HW-verified layout]
  const float bval = bias[nt * 2 + wn];
  const int h = nt * 2 + wn;
#pragma unroll
  for (int mi = 0; mi < 4; ++mi) {
#pragma unroll
    for (int nj = 0; nj < 4; ++nj) {
#pragma unroll
      for (int j = 0; j < 4; ++j) {
        int r = mt * 128 + wm * 64 + mi * 16 + lg * 4 + j;   // token index
        int dd = nj * 16 + lr;                               // dim within head
        int bb = r >> 10, lpos = r & (NL - 1);
        float val = (acc[mi][nj][j] + bval) * scale;
        if (z < 2)
          Out[((bb * NH + h) * NL + lpos) * NHD + dd] = f2bf(val);
        else
          Out[((bb * NH + h) * NHD + dd) * NL + lpos] = f2bf(val);
      }
    }
  }
}

// ---------------------------------------------------------------------------
// Flash attention, swapped-operand + exp2-domain + defer-max + async staging
// + LDS slot-swizzle (s' = (s + 2*(row&7))&7 on K/V/P, write & read sides)
// targeting the measured 5.77M bank-conflict cycles.
// ---------------------------------------------------------------------------
__global__ __launch_bounds__(256) void attn_kernel(
    const unsigned short* __restrict__ Q,
    const unsigned short* __restrict__ K,
    const unsigned short* __restrict__ Vt,
    float* __restrict__ Out) {
  __shared__ unsigned short Ks[64 * 72];
  __shared__ unsigned short Vs[64 * 72];
  __shared__ unsigned short Ps[64 * 72];

  const int qt = blockIdx.x;   // 0..15
  const int bh = blockIdx.y;   // 0..63
  const int bb = bh >> 3, h = bh & 7;
  const int tid = threadIdx.x;
  const int w = tid >> 6;
  const int lane = tid & 63;
  const int lg = lane >> 4, lr = lane & 15;
  const int qrow0 = qt * 64 + w * 16;

  // Q B-fragment: row = lr, k-slice = lg*8 within each 32-block
  bf16x8v qf[2];
#pragma unroll
  for (int kk = 0; kk < 2; ++kk)
    qf[kk] = *(const bf16x8v*)(Q + ((size_t)bh * NL + qrow0 + lr) * NHD + kk * 32 + lg * 8);

  // Staging: rows r0, r0+32 (same row&7), swizzled 16B-slot destination.
  const int r0 = tid >> 3;
  const int c8 = tid & 7;
  const unsigned short* kp0 = K + (size_t)bh * NL * NHD + r0 * NHD + c8 * 8;
  const unsigned short* vp0 = Vt + ((size_t)bh * NHD + r0) * NL + c8 * 8;
  const int sw_st = 8 * ((c8 + 2 * (r0 & 7)) & 7);
  unsigned short* kdst = Ks + r0 * 72 + sw_st;
  unsigned short* vdst = Vs + r0 * 72 + sw_st;

  float m_ = -1e30f, lsum = 0.0f;
  f32x4 o[4] = {};
  int4 ka, kc, va, vc;

#define KVLOADS(kv)                                             \
  ka = *(const int4*)(kp0 + (kv) * 64 * NHD);                   \
  kc = *(const int4*)(kp0 + (kv) * 64 * NHD + 32 * NHD);        \
  va = *(const int4*)(vp0 + (kv) * 64);                         \
  vc = *(const int4*)(vp0 + (kv) * 64 + 32 * NL);

  KVLOADS(0)
  for (int kv = 0; kv < 16; ++kv) {
    if (kv) __syncthreads();          // all waves done with previous tile
    *(int4*)(kdst)           = ka;
    *(int4*)(kdst + 32 * 72) = kc;
    *(int4*)(vdst)           = va;
    *(int4*)(vdst + 32 * 72) = vc;
    if (kv < 15) { KVLOADS(kv + 1) }  // next tile loads fly during compute
    __syncthreads();

    // S^T = K * Q^T (log2 units; scale*log2e folded into Q)
    f32x4 s[4] = {};
    __builtin_amdgcn_s_setprio(1);
#pragma unroll
    for (int kk = 0; kk < 2; ++kk) {
#pragma unroll
      for (int nb = 0; nb < 4; ++nb) {
        int row = nb * 16 + lr;
        bf16x8v kf = *(const bf16x8v*)(Ks + row * 72 +
                                       8 * ((4 * kk + lg + 2 * (row & 7)) & 7));
        s[nb] = __builtin_amdgcn_mfma_f32_16x16x32_bf16(kf, qf[kk], s[nb], 0, 0, 0);
      }
    }
    __builtin_amdgcn_s_setprio(0);

    // Online softmax, exp2 domain, defer-max
    float tm;
    {
      float a0 = fmaxf(s[0][0], s[0][1]), a1 = fmaxf(s[0][2], s[0][3]);
      float a2 = fmaxf(s[1][0], s[1][1]), a3 = fmaxf(s[1][2], s[1][3]);
      float a4 = fmaxf(s[2][0], s[2][1]), a5 = fmaxf(s[2][2], s[2][3]);
      float a6 = fmaxf(s[3][0], s[3][1]), a7 = fmaxf(s[3][2], s[3][3]);
      float c0 = fmaxf(fmaxf(a0, a1), fmaxf(a2, a3));
      float c1 = fmaxf(fmaxf(a4, a5), fmaxf(a6, a7));
      tm = fmaxf(c0, c1);
    }
    tm = fmaxf(tm, __shfl_xor(tm, 16, 64));
    tm = fmaxf(tm, __shfl_xor(tm, 32, 64));
    if (__any(tm > m_ + 8.0f)) {
      float nm = fmaxf(m_, tm);
      float corr = exp2f(m_ - nm);
      m_ = nm;
      lsum *= corr;
#pragma unroll
      for (int db = 0; db < 4; ++db)
#pragma unroll
        for (int j = 0; j < 4; ++j) o[db][j] *= corr;
    }
#pragma unroll
    for (int nb = 0; nb < 4; ++nb)
#pragma unroll
      for (int j = 0; j < 4; ++j)
        s[nb][j] = exp2f(s[nb][j] - m_);
    float ts;
    {
      float a0 = s[0][0] + s[0][1], a1 = s[0][2] + s[0][3];
      float a2 = s[1][0] + s[1][1], a3 = s[1][2] + s[1][3];
      float a4 = s[2][0] + s[2][1], a5 = s[2][2] + s[2][3];
      float a6 = s[3][0] + s[3][1], a7 = s[3][2] + s[3][3];
      ts = ((a0 + a1) + (a2 + a3)) + ((a4 + a5) + (a6 + a7));
    }
    ts += __shfl_xor(ts, 16, 64);
    ts += __shfl_xor(ts, 32, 64);
    lsum += ts;

    // P row q=lr -> LDS packed u32, swizzled slot (wave-private rows)
    {
      int prow = w * 16 + lr;
      unsigned short* pbase = Ps + prow * 72;
      int key = 2 * (lr & 7);
#pragma unroll
      for (int nb = 0; nb < 4; ++nb)
#pragma unroll
        for (int hh = 0; hh < 2; ++hh) {
          int slot = 2 * nb + (lg >> 1);
          *(unsigned*)(pbase + 8 * ((slot + key) & 7) + (lg & 1) * 4 + 2 * hh) =
              pack_bf16x2(s[nb][2 * hh], s[nb][2 * hh + 1]);
        }
    }

    // O^T += V^T * P^T
    __builtin_amdgcn_s_setprio(1);
#pragma unroll
    for (int kk = 0; kk < 2; ++kk) {
      int prow = w * 16 + lr;
      bf16x8v pf = *(const bf16x8v*)(Ps + prow * 72 +
                                     8 * ((4 * kk + lg + 2 * (lr & 7)) & 7));
#pragma unroll
      for (int db = 0; db < 4; ++db) {
        int row = db * 16 + lr;
        bf16x8v vf = *(const bf16x8v*)(Vs + row * 72 +
                                       8 * ((4 * kk + lg + 2 * (row & 7)) & 7));
        o[db] = __builtin_amdgcn_mfma_f32_16x16x32_bf16(vf, pf, o[db], 0, 0, 0);
      }
    }
    __builtin_amdgcn_s_setprio(0);
  }
#undef KVLOADS

  // Normalize (scalar per lane) and write out[B, L, 512] f32 as float4s
  float inv = 1.0f / lsum;
  int q = qrow0 + lr;
#pragma unroll
  for (int db = 0; db < 4; ++db) {
    f32x4 ov;
#pragma unroll
    for (int j = 0; j < 4; ++j) ov[j] = o[db][j] * inv;
    *(f32x4*)(Out + (size_t)(bb * NL + q) * NC + h * NHD + db * 16 + lg * 4) = ov;
  }
}

// ---------------------------------------------------------------------------
extern "C" void kernel_launch(void* const* d_in, const int* in_sizes, int n_in,
                              void* d_out, int out_size, void* d_ws, size_t ws_size,
                              hipStream_t stream) {
  const float* x  = (const float*)d_in[0];
  const float* Wq = (const float*)d_in[1];
  const float* bq = (const float*)d_in[2];
  const float* Wk = (const float*)d_in[3];
  const float* bk = (const float*)d_in[4];
  const float* Wv = (const float*)d_in[5];
  const float* bv = (const float*)d_in[6];
  float* out = (float*)d_out;

  // Workspace: only q/k/v bf16 buffers now (8.4 MB each)
  unsigned short* qg = (unsigned short*)d_ws;
  unsigned short* kg = qg + (size_t)NB * NH * NL * NHD;
  unsigned short* vg = kg + (size_t)NB * NH * NL * NHD;

  gemm_qkv_fused_kernel<<<dim3(4, 64, 3), 256, 0, stream>>>(
      x, Wq, Wk, Wv, bq, bk, bv, qg, kg, vg);

  attn_kernel<<<dim3(16, 64), 256, 0, stream>>>(qg, kg, vg, out);
}